// Round 5
// baseline (218.035 us; speedup 1.0000x reference)
//
#include <hip/hip_runtime.h>
#include <hip/hip_bf16.h>
#include <math.h>

#define B_G   16
#define N_A   512
#define M_AT  8192
#define FD    128
#define HD    64
#define DD    16
#define SEIN  95
#define EHIN  159
#define NLUT  512
#define DMAXF 140.0f

__device__ __forceinline__ float silu_f(float z) { return z / (1.f + __expf(-z)); }

// ================================================================ k_front
// blocks 0..1023: src MLP, 8 atoms each (2 waves x 4 atoms), weights from global.
// blocks 1024..1027: kernel-LUT (512 entries, 128/block) + zero out[16].
__global__ __launch_bounds__(128) void k_front(
    const float* __restrict__ x,
    const float* __restrict__ g, const float* __restrict__ bb,
    const float* __restrict__ w1, const float* __restrict__ b1,
    const float* __restrict__ w2, const float* __restrict__ b2,
    const float* __restrict__ lng, const float* __restrict__ lnb,
    const float* __restrict__ k_screen,
    const float* __restrict__ kg_w1, const float* __restrict__ kg_b1,
    const float* __restrict__ kg_w2, const float* __restrict__ kg_b2,
    float* __restrict__ srcout, float* __restrict__ partials,
    float2* __restrict__ lut, float* __restrict__ out) {
  int t = threadIdx.x;

  __shared__ __align__(16) float xns[2][FD][5];   // padded [k][a]
  __shared__ __align__(16) float hb[2][HD][5];
  __shared__ float psum[2][16];
  __shared__ float w1l[320], b1l[32], w2l[32];

  if (blockIdx.x >= 1024) {
    // ---------------- LUT block ----------------
    int lb = blockIdx.x - 1024;
    if (lb == 0 && t < B_G) out[t] = 0.f;
    for (int idx = t; idx < 320; idx += 128) w1l[idx] = kg_w1[idx];
    if (t < 32) { b1l[t] = kg_b1[t]; w2l[t] = kg_w2[t]; }
    __syncthreads();
    int i = lb * 128 + t;
    float step = DMAXF / (float)(NLUT - 1);
    float ksv = k_screen[0];
    float screening = fmaxf(ksv, 0.f) + log1pf(expf(-fabsf(ksv)));
    float b2v = kg_b2[0];
    float vals[2];
#pragma unroll
    for (int e = 0; e < 2; ++e) {
      int ii = min(i + e, NLUT - 1);
      float d = (float)ii * step;
      float base = expf(-screening * d) / fmaxf(d, 1e-6f);
      float gin[10];
      gin[0] = d * (1.f / 5.0f);
      gin[1] = d * (1.f / 40.0f);
#pragma unroll
      for (int kk = 0; kk < 8; ++kk) {
        float u = d - (5.0f + 5.0f * (float)kk);
        gin[2 + kk] = expf(-(1.f / 25.f) * u * u);
      }
      float accv = 0.f;
      for (int h = 0; h < 32; ++h) {
        float z = b1l[h];
#pragma unroll
        for (int kk = 0; kk < 10; ++kk) z += gin[kk] * w1l[kk * 32 + h];
        accv += silu_f(z) * w2l[h];
      }
      vals[e] = base * (1.f + tanhf(accv + b2v));
    }
    lut[i] = make_float2(vals[0], vals[1] - vals[0]);
    return;
  }

  // ---------------- src block: 8 atoms, wave handles 4 ----------------
  int wave = t >> 6, lane = t & 63;
  int a = lane >> 4;        // atom within wave (0..3)
  int s = lane & 15;        // dim-chunk / h-quad / c index
  int aBase = blockIdx.x * 8 + wave * 4;

  // LN(128): 16 lanes per atom, 8 dims each (s*8 .. s*8+7)
  float xr[8];
  {
    const float4* xp = (const float4*)(x + (size_t)(aBase + a) * FD + s * 8);
    float4 v0 = xp[0], v1 = xp[1];
    xr[0]=v0.x; xr[1]=v0.y; xr[2]=v0.z; xr[3]=v0.w;
    xr[4]=v1.x; xr[5]=v1.y; xr[6]=v1.z; xr[7]=v1.w;
  }
  float sm_ = 0.f;
#pragma unroll
  for (int i = 0; i < 8; ++i) sm_ += xr[i];
  sm_ += __shfl_xor(sm_, 1); sm_ += __shfl_xor(sm_, 2);
  sm_ += __shfl_xor(sm_, 4); sm_ += __shfl_xor(sm_, 8);
  float m = sm_ * (1.f / 128.f);
  float v2 = 0.f;
#pragma unroll
  for (int i = 0; i < 8; ++i) { float d = xr[i] - m; v2 += d * d; }
  v2 += __shfl_xor(v2, 1); v2 += __shfl_xor(v2, 2);
  v2 += __shfl_xor(v2, 4); v2 += __shfl_xor(v2, 8);
  float inv = rsqrtf(v2 * (1.f / 128.f) + 1e-5f);
#pragma unroll
  for (int i = 0; i < 8; ++i) {
    int k = s * 8 + i;
    xns[wave][k][a] = (xr[i] - m) * inv * g[k] + bb[k];
  }

  // GEMM1 128->64: lane = (h-quad s, atom a); weights streamed from global
  float acc[4] = {0.f, 0.f, 0.f, 0.f};
#pragma unroll 8
  for (int k = 0; k < FD; ++k) {
    float4 wv = ((const float4*)(w1 + (size_t)k * HD))[s];
    float xa = xns[wave][k][a];
    acc[0] += wv.x * xa; acc[1] += wv.y * xa;
    acc[2] += wv.z * xa; acc[3] += wv.w * xa;
  }
  {
    float4 bv = ((const float4*)b1)[s];
    hb[wave][s * 4 + 0][a] = silu_f(acc[0] + bv.x);
    hb[wave][s * 4 + 1][a] = silu_f(acc[1] + bv.y);
    hb[wave][s * 4 + 2][a] = silu_f(acc[2] + bv.z);
    hb[wave][s * 4 + 3][a] = silu_f(acc[3] + bv.w);
  }

  // GEMM2 64->16: lane = (c = s, atom a)
  float e = 0.f;
#pragma unroll 8
  for (int k = 0; k < HD; ++k) e += hb[wave][k][a] * w2[k * DD + s];
  float val = e + b2[s];

  // LN(16) across the 16 c-lanes of each atom
  float smv = val;
  smv += __shfl_xor(smv, 1); smv += __shfl_xor(smv, 2);
  smv += __shfl_xor(smv, 4); smv += __shfl_xor(smv, 8);
  float mm = smv * (1.f / 16.f);
  float dv = val - mm;
  float vv = dv * dv;
  vv += __shfl_xor(vv, 1); vv += __shfl_xor(vv, 2);
  vv += __shfl_xor(vv, 4); vv += __shfl_xor(vv, 8);
  float iv = rsqrtf(vv * (1.f / 16.f) + 1e-5f);
  float ov = dv * iv * lng[s] + lnb[s];
  srcout[(size_t)(aBase + a) * DD + s] = ov;

  // per-block partial sums (for graph-mean downstream)
  float lsum = ov;
  lsum += __shfl_xor(lsum, 16); lsum += __shfl_xor(lsum, 32);
  if (lane < 16) psum[wave][lane] = lsum;
  __syncthreads();
  if (t < 16) partials[(size_t)blockIdx.x * 16 + t] = psum[0][t] + psum[1][t];
}

// ================================================================ k_pairs_tail
// 4 atoms per 256-thread block (one wave per atom). Pair loop + full tail MLPs.
__global__ __launch_bounds__(256) void k_pairs_tail(
    const float* __restrict__ pos, const float* __restrict__ src,
    const float2* __restrict__ lut, const float* __restrict__ partials,
    const float* __restrict__ se_ln_g, const float* __restrict__ se_ln_b,
    const float* __restrict__ se_w1, const float* __restrict__ se_b1,
    const float* __restrict__ se_w2, const float* __restrict__ se_b2,
    const float* __restrict__ eh_ln_g, const float* __restrict__ eh_ln_b,
    const float* __restrict__ eh_w1, const float* __restrict__ eh_b1,
    const float* __restrict__ eh_w2, const float* __restrict__ eh_b2,
    const float* __restrict__ far_gate, const float* __restrict__ energy_scale,
    float* __restrict__ out) {
  int gph = blockIdx.x >> 7;
  int blk = blockIdx.x & 127;
  int t = threadIdx.x, wave = t >> 6, lane = t & 63;
  int i_local = blk * 4 + wave;

  __shared__ __align__(16) float sp[N_A * 3];      // 6 KB
  __shared__ __align__(16) float ss[N_A * DD];     // 32 KB
  __shared__ __align__(16) float2 luts[NLUT];      // 4 KB
  __shared__ float smean[16];
  __shared__ __align__(16) float einL[4][160];     // raw shell rows 64..158; later full ein
  __shared__ __align__(16) float shnL[4][96];
  __shared__ __align__(16) float hbL[4][64];
  __shared__ float redv[4];

  for (int idx = t; idx < N_A * 3 / 4; idx += 256)
    ((float4*)sp)[idx] = ((const float4*)(pos + (size_t)gph * N_A * 3))[idx];
  for (int idx = t; idx < N_A * DD / 4; idx += 256)
    ((float4*)ss)[idx] = ((const float4*)(src + (size_t)gph * N_A * DD))[idx];
  if (t < NLUT / 2) ((float4*)luts)[t] = ((const float4*)lut)[t];
  if (t < 64) {  // graph mean from 64 block-partials
    int c = t & 15, grp = t >> 4;
    float sm = 0.f;
#pragma unroll
    for (int kk = 0; kk < 16; ++kk)
      sm += partials[(size_t)(gph * 64 + grp * 16 + kk) * 16 + c];
    sm += __shfl_xor(sm, 16); sm += __shfl_xor(sm, 32);
    if (t < 16) smean[c] = sm * (1.f / 512.f);
  }
  __syncthreads();

  // ---------------- pair loop (single phase) ----------------
  // lane = (jlow = lane&15, cq = lane>>4). Each lane: 32 j's (j = jj*16+jlow),
  // 4 dims (cq*4..+3). Scalar stats duplicated 4x across cq -> /4 after reduce.
  int jlow = lane & 15, cq = lane >> 4;
  float px = sp[i_local * 3], py = sp[i_local * 3 + 1], pz = sp[i_local * 3 + 2];
  float accq[5][4] = {};
  float cnt[5] = {0,0,0,0,0}, sdv[5] = {0,0,0,0,0}, sdd[5] = {0,0,0,0,0}, swq[5] = {0,0,0,0,0};
  const float lscale = (float)(NLUT - 1) / DMAXF;

#pragma unroll 8
  for (int jj = 0; jj < 32; ++jj) {
    int j = jj * 16 + jlow;
    float dx = px - sp[j * 3], dy = py - sp[j * 3 + 1], dz = pz - sp[j * 3 + 2];
    float d2 = dx * dx + dy * dy + dz * dz + 1e-12f;
    float d = sqrtf(d2);
    bool valid = (j != i_local) && (d >= 5.0f);
    int tq = (d >= 10.f) + (d >= 20.f) + (d >= 40.f) + (d >= 80.f);
    float xq = d * lscale;
    int i0 = min((int)xq, NLUT - 2);
    float f = xq - (float)i0;
    float2 L = luts[i0];
    float w = valid ? (L.x + L.y * f) : 0.f;
    float dm = valid ? d : 0.f;
    float ddm = valid ? d * d : 0.f;
    float cm = valid ? 1.f : 0.f;
    float4 sv = *(const float4*)&ss[j * DD + cq * 4];
#pragma unroll
    for (int q = 0; q < 5; ++q) {
      bool mq = (tq == q);
      float wq = mq ? w : 0.f;
      accq[q][0] += wq * sv.x; accq[q][1] += wq * sv.y;
      accq[q][2] += wq * sv.z; accq[q][3] += wq * sv.w;
      cnt[q] += mq ? cm : 0.f;
      sdv[q] += mq ? dm : 0.f;
      sdd[q] += mq ? ddm : 0.f;
      swq[q] += wq;
    }
  }
  // weighted-source: reduce over jlow only (cq groups hold different dims)
#pragma unroll
  for (int q = 0; q < 5; ++q)
#pragma unroll
    for (int i = 0; i < 4; ++i) {
      float v = accq[q][i];
      v += __shfl_xor(v, 1); v += __shfl_xor(v, 2);
      v += __shfl_xor(v, 4); v += __shfl_xor(v, 8);
      accq[q][i] = v;
    }
  // scalar stats: reduce over all 64 lanes, then /4 (cq duplication)
#pragma unroll
  for (int q = 0; q < 5; ++q) {
#pragma unroll
    for (int o = 32; o > 0; o >>= 1) {
      cnt[q] += __shfl_xor(cnt[q], o);
      sdv[q] += __shfl_xor(sdv[q], o);
      sdd[q] += __shfl_xor(sdd[q], o);
      swq[q] += __shfl_xor(swq[q], o);
    }
    cnt[q] *= 0.25f; sdv[q] *= 0.25f; sdd[q] *= 0.25f; swq[q] *= 0.25f;
  }

  // ---------------- raw shell -> einL rows 64..158 ----------------
  if (jlow == 0) {
#pragma unroll
    for (int q = 0; q < 5; ++q) {
      float denom = fmaxf(cnt[q], 1.f);
#pragma unroll
      for (int i = 0; i < 4; ++i) {
        int c = cq * 4 + i;
        einL[wave][64 + q * 19 + c] = (accq[q][i] - smean[c] * swq[q]) / denom;
      }
    }
  }
  if (lane < 5) {
    int q = lane;
    float denom = fmaxf(cnt[q], 1.f);
    einL[wave][64 + q * 19 + 16] = cnt[q];
    einL[wave][64 + q * 19 + 17] = sdv[q] / denom;
    einL[wave][64 + q * 19 + 18] = sqrtf(sdd[q] / denom + 1e-12f);
  }

  // ---------------- LN(95) -> shnL ----------------
  {
    float v0 = einL[wave][64 + lane];
    float v1 = (lane < 31) ? einL[wave][128 + lane] : 0.f;
    float s1 = v0 + v1, sq = v0 * v0 + v1 * v1;
#pragma unroll
    for (int o = 32; o > 0; o >>= 1) { s1 += __shfl_xor(s1, o); sq += __shfl_xor(sq, o); }
    float mn = s1 * (1.f / (float)SEIN);
    float var = sq * (1.f / (float)SEIN) - mn * mn;
    float invv = rsqrtf(var + 1e-5f);
    shnL[wave][lane] = (v0 - mn) * invv * se_ln_g[lane] + se_ln_b[lane];
    if (lane < 31)
      shnL[wave][64 + lane] = (v1 - mn) * invv * se_ln_g[64 + lane] + se_ln_b[64 + lane];
  }

  // ---------------- se hidden 95->64 (h = lane) ----------------
  {
    float z = se_b1[lane];
#pragma unroll 5
    for (int k = 0; k < SEIN; ++k) z += shnL[wave][k] * se_w1[(size_t)k * HD + lane];
    hbL[wave][lane] = silu_f(z);
  }

  // ---------------- 64->16 emb; build ein rows 0..63 ----------------
  {
    int c = lane & 15, kq = lane >> 4;
    float e = 0.f;
#pragma unroll
    for (int i = 0; i < 16; ++i) {
      int k = kq * 16 + i;
      e += hbL[wave][k] * se_w2[k * DD + c];
    }
    e += __shfl_down(e, 32);
    e += __shfl_down(e, 16);
    if (lane < 16) {
      float ev = e + se_b2[lane];
      float svv = ss[i_local * DD + lane] - smean[lane];
      einL[wave][lane] = svv;
      einL[wave][16 + lane] = ev;
      einL[wave][32 + lane] = svv * ev;
      einL[wave][48 + lane] = svv - ev;
    }
  }

  // ---------------- LN(159) in-place ----------------
  {
    float u0 = einL[wave][lane];
    float u1 = einL[wave][64 + lane];
    float u2 = (lane < 31) ? einL[wave][128 + lane] : 0.f;
    float s1 = u0 + u1 + u2, sq = u0 * u0 + u1 * u1 + u2 * u2;
#pragma unroll
    for (int o = 32; o > 0; o >>= 1) { s1 += __shfl_xor(s1, o); sq += __shfl_xor(sq, o); }
    float mn = s1 * (1.f / (float)EHIN);
    float var = sq * (1.f / (float)EHIN) - mn * mn;
    float invv = rsqrtf(var + 1e-5f);
    einL[wave][lane] = (u0 - mn) * invv * eh_ln_g[lane] + eh_ln_b[lane];
    einL[wave][64 + lane] = (u1 - mn) * invv * eh_ln_g[64 + lane] + eh_ln_b[64 + lane];
    if (lane < 31)
      einL[wave][128 + lane] = (u2 - mn) * invv * eh_ln_g[128 + lane] + eh_ln_b[128 + lane];
  }

  // ---------------- eh hidden 159->64, dot w2, reduce ----------------
  {
    float z2 = eh_b1[lane];
#pragma unroll 3
    for (int k = 0; k < EHIN; ++k) z2 += einL[wave][k] * eh_w1[(size_t)k * HD + lane];
    float pa = silu_f(z2) * eh_w2[lane];
#pragma unroll
    for (int o = 32; o > 0; o >>= 1) pa += __shfl_xor(pa, o);
    if (lane == 0) redv[wave] = pa + eh_b2[0];
  }
  __syncthreads();
  if (t == 0) {
    float tot = redv[0] + redv[1] + redv[2] + redv[3];
    atomicAdd(&out[gph], tot * tanhf(far_gate[0]) * expf(energy_scale[0]));
  }
}

// ================================================================ launch
extern "C" void kernel_launch(void* const* d_in, const int* in_sizes, int n_in,
                              void* d_out, int out_size, void* d_ws, size_t ws_size,
                              hipStream_t stream) {
  const float* x         = (const float*)d_in[0];
  const float* pos       = (const float*)d_in[1];
  const float* in_ln_g   = (const float*)d_in[4];
  const float* in_ln_b   = (const float*)d_in[5];
  const float* src_w1    = (const float*)d_in[6];
  const float* src_b1    = (const float*)d_in[7];
  const float* src_w2    = (const float*)d_in[8];
  const float* src_b2    = (const float*)d_in[9];
  const float* src_ln_g  = (const float*)d_in[10];
  const float* src_ln_b  = (const float*)d_in[11];
  const float* se_ln_g   = (const float*)d_in[12];
  const float* se_ln_b   = (const float*)d_in[13];
  const float* se_w1     = (const float*)d_in[14];
  const float* se_b1     = (const float*)d_in[15];
  const float* se_w2     = (const float*)d_in[16];
  const float* se_b2     = (const float*)d_in[17];
  const float* eh_ln_g   = (const float*)d_in[18];
  const float* eh_ln_b   = (const float*)d_in[19];
  const float* eh_w1     = (const float*)d_in[20];
  const float* eh_b1     = (const float*)d_in[21];
  const float* eh_w2     = (const float*)d_in[22];
  const float* eh_b2     = (const float*)d_in[23];
  const float* k_screen  = (const float*)d_in[24];
  const float* kg_w1     = (const float*)d_in[25];
  const float* kg_b1     = (const float*)d_in[26];
  const float* kg_w2     = (const float*)d_in[27];
  const float* kg_b2     = (const float*)d_in[28];
  const float* far_gate  = (const float*)d_in[29];
  const float* en_scale  = (const float*)d_in[30];
  float* out = (float*)d_out;

  float* ws_src   = (float*)d_ws;                            // M*16
  float* ws_part  = ws_src + (size_t)M_AT * DD;              // 1024*16
  float2* ws_lut  = (float2*)(ws_part + 1024 * 16);          // NLUT float2

  k_front<<<1028, 128, 0, stream>>>(x, in_ln_g, in_ln_b, src_w1, src_b1,
                                    src_w2, src_b2, src_ln_g, src_ln_b,
                                    k_screen, kg_w1, kg_b1, kg_w2, kg_b2,
                                    ws_src, ws_part, ws_lut, out);
  k_pairs_tail<<<B_G * (N_A / 4), 256, 0, stream>>>(
      pos, ws_src, ws_lut, ws_part,
      se_ln_g, se_ln_b, se_w1, se_b1, se_w2, se_b2,
      eh_ln_g, eh_ln_b, eh_w1, eh_b1, eh_w2, eh_b2,
      far_gate, en_scale, out);
}